// Round 3
// baseline (619.525 us; speedup 1.0000x reference)
//
#include <hip/hip_runtime.h>
#include <hip/hip_bf16.h>
#include <hip/hip_fp16.h>
#include <math.h>

// QAT GPT2 MLP + LoRA on MI355X — fp32 inputs/outputs (verified via threshold
// arithmetic: bf16 eps-floor not active => no bf16 tensors in the problem).
// Dims: M=8192 (4x2048), n_embd=1024, d_ff=4096, r=8.
// Pipeline:
//   memset scales -> absmax(x), absmax(Wfc), absmax(Wproj)
//   quant_x (+t1 = x@Afc^T) ; quant_w(Wfc), quant_w(Wproj)  [bf16-int out]
//   gemm1: bf16 MFMA on quantized ints (exact integer arith); epilogue:
//          *s_x*s_w + bias + 2*t1.Bfc, exact-erf GELU, store h as FP16,
//          absmax(h fp32) -> slot 3
//   quant_h (fp16 -> bf16-int in place) + t2 = h@Aproj^T
//   gemm2: epilogue *s + bias + 2*t2.Bproj, store fp32 -> d_out
// Quantized values are integers in [-128,127]: exact in bf16; fp32 MFMA
// accumulation of their products is exact integer arithmetic (|sum| << 2^24).

typedef unsigned short u16;
typedef unsigned int u32;
typedef short bf16x8 __attribute__((ext_vector_type(8)));
typedef float f32x4 __attribute__((ext_vector_type(4)));

#define ASYNC16(gp, lp)                                                        \
  __builtin_amdgcn_global_load_lds(                                            \
      (__attribute__((address_space(1))) void*)(gp),                           \
      (__attribute__((address_space(3))) void*)(lp), 16, 0, 0)

// quantize: q = clip(rint(v/s), -128, 127); q integer -> bf16 bits exact
// (integers |q|<=255 need <=8 mantissa bits; fp32 low mantissa is zero).
__device__ __forceinline__ u16 quant1(float v, float inv) {
  float q = rintf(v * inv);
  q = fminf(fmaxf(q, -128.0f), 127.0f);
  return (u16)(__float_as_uint(q) >> 16);
}

__device__ __forceinline__ float load_scale(const u32* slot) {
  return fmaxf(__uint_as_float(*slot) * (1.0f / 127.0f), 1e-8f);
}

// -------------------- absmax over fp32 tensor (float4 grid-stride) ----------
__global__ void absmax_kernel(const float* __restrict__ x, int n4,
                              u32* __restrict__ slot) {
  float m = 0.0f;
  int stride = gridDim.x * blockDim.x;
  for (int i = blockIdx.x * blockDim.x + threadIdx.x; i < n4; i += stride) {
    float4 v = ((const float4*)x)[i];
    m = fmaxf(m, fmaxf(fmaxf(fabsf(v.x), fabsf(v.y)),
                       fmaxf(fabsf(v.z), fabsf(v.w))));
  }
#pragma unroll
  for (int off = 32; off > 0; off >>= 1) m = fmaxf(m, __shfl_down(m, off));
  __shared__ float wmax[4];
  int lane = threadIdx.x & 63, wave = threadIdx.x >> 6;
  if (lane == 0) wmax[wave] = m;
  __syncthreads();
  if (threadIdx.x == 0) {
    m = fmaxf(fmaxf(wmax[0], wmax[1]), fmaxf(wmax[2], wmax[3]));
    atomicMax(slot, __float_as_uint(m));  // positive floats: bit-monotone
  }
}

// -------------------- quantize W (fp32 in, bf16-int out) --------------------
__global__ void quant_w_kernel(const float* __restrict__ w, int n4,
                               const u32* __restrict__ slot,
                               u16* __restrict__ q) {
  float inv = 1.0f / load_scale(slot);
  int stride = gridDim.x * blockDim.x;
  for (int i = blockIdx.x * blockDim.x + threadIdx.x; i < n4; i += stride) {
    float4 v = ((const float4*)w)[i];
    ushort4 o;
    o.x = quant1(v.x, inv);
    o.y = quant1(v.y, inv);
    o.z = quant1(v.z, inv);
    o.w = quant1(v.w, inv);
    ((ushort4*)q)[i] = o;
  }
}

// ---- quantize x + t1[m][r] = sum_i x[m,i]*Afc[r,i]  (block per row) --------
__global__ void quant_x_t1_kernel(const float* __restrict__ x,
                                  const float* __restrict__ A,  // [8][1024]
                                  const u32* __restrict__ slot,
                                  u16* __restrict__ q,
                                  float* __restrict__ t1) {
  int row = blockIdx.x, tid = threadIdx.x;
  float inv = 1.0f / load_scale(slot);
  float4 v = ((const float4*)(x + (long)row * 1024))[tid];
  ushort4 o;
  o.x = quant1(v.x, inv);
  o.y = quant1(v.y, inv);
  o.z = quant1(v.z, inv);
  o.w = quant1(v.w, inv);
  ((ushort4*)(q + (long)row * 1024))[tid] = o;
  float p[8];
#pragma unroll
  for (int r = 0; r < 8; r++) {
    float4 a = ((const float4*)(A + r * 1024))[tid];
    p[r] = v.x * a.x + v.y * a.y + v.z * a.z + v.w * a.w;
  }
#pragma unroll
  for (int r = 0; r < 8; r++)
#pragma unroll
    for (int off = 32; off > 0; off >>= 1) p[r] += __shfl_down(p[r], off);
  __shared__ float red[4][8];
  int lane = tid & 63, wave = tid >> 6;
  if (lane == 0) {
#pragma unroll
    for (int r = 0; r < 8; r++) red[wave][r] = p[r];
  }
  __syncthreads();
  if (tid < 8)
    t1[(long)row * 8 + tid] =
        red[0][tid] + red[1][tid] + red[2][tid] + red[3][tid];
}

// ---- quantize h (fp16 in, bf16-int out, in place) + t2 = h@Aproj^T ---------
__global__ void quant_h_t2_kernel(u16* __restrict__ h,  // [8192][4096] fp16
                                  const float* __restrict__ A,  // [8][4096]
                                  const u32* __restrict__ slot,
                                  float* __restrict__ t2) {
  int row = blockIdx.x, tid = threadIdx.x;
  float inv = 1.0f / load_scale(slot);
  u16* hp = h + (long)row * 4096 + tid * 16;
  uint4 u0 = ((const uint4*)hp)[0];
  uint4 u1 = ((const uint4*)hp)[1];
  u32 uu[8] = {u0.x, u0.y, u0.z, u0.w, u1.x, u1.y, u1.z, u1.w};
  float hv[16];
#pragma unroll
  for (int e = 0; e < 8; e++) {
    __half2 hh = *(__half2*)&uu[e];
    float2 f = __half22float2(hh);
    hv[2 * e] = f.x;
    hv[2 * e + 1] = f.y;
  }
  // t2 partials (LoRA path, rank 8)
  const float* Ab = A + tid * 16;
  float p[8];
#pragma unroll
  for (int r = 0; r < 8; r++) {
    const float4* Ar = (const float4*)(Ab + r * 4096);
    float s = 0.0f;
#pragma unroll
    for (int c = 0; c < 4; c++) {
      float4 a = Ar[c];
      s += a.x * hv[c * 4 + 0] + a.y * hv[c * 4 + 1] + a.z * hv[c * 4 + 2] +
           a.w * hv[c * 4 + 3];
    }
    p[r] = s;
  }
  // quantize in place
  u32 qu[8];
#pragma unroll
  for (int e = 0; e < 8; e++) {
    u16 q0 = quant1(hv[2 * e], inv);
    u16 q1 = quant1(hv[2 * e + 1], inv);
    qu[e] = (u32)q0 | ((u32)q1 << 16);
  }
  uint4 w0 = {qu[0], qu[1], qu[2], qu[3]};
  uint4 w1 = {qu[4], qu[5], qu[6], qu[7]};
  ((uint4*)hp)[0] = w0;
  ((uint4*)hp)[1] = w1;
#pragma unroll
  for (int r = 0; r < 8; r++)
#pragma unroll
    for (int off = 32; off > 0; off >>= 1) p[r] += __shfl_down(p[r], off);
  __shared__ float red[4][8];
  int lane = tid & 63, wave = tid >> 6;
  if (lane == 0) {
#pragma unroll
    for (int r = 0; r < 8; r++) red[wave][r] = p[r];
  }
  __syncthreads();
  if (tid < 8)
    t2[(long)row * 8 + tid] =
        red[0][tid] + red[1][tid] + red[2][tid] + red[3][tid];
}

// -------------------- main GEMM: C = Aq * Bq^T, 128x128 tile ----------------
// A: [M][K] bf16-int row-major, B: [N][K] bf16-int row-major (K-major both).
// MODE 0: *scale + bias + 2*t.Bl, exact-erf GELU, store FP16 h, absmax(h).
// MODE 1: *scale + bias + 2*t.Bl, store fp32 to d_out.
template <int MODE>
__launch_bounds__(256) __global__
    void gemm_kernel(const u16* __restrict__ A, const u16* __restrict__ B,
                     int N, int K, const float* __restrict__ bias,
                     const float* __restrict__ tl,   // [M][8] f32
                     const float* __restrict__ Bl,   // [N][8] f32
                     const u32* __restrict__ scales, int sa, int sb,
                     void* __restrict__ outp, u32* __restrict__ hmax) {
  __shared__ u16 As[128 * 64];
  __shared__ u16 Bs[128 * 64];
  __shared__ u32 bmax;
  int tid = threadIdx.x;
  int lane = tid & 63, wave = tid >> 6;
  int quad = lane >> 4, l15 = lane & 15;
  int wm = (wave & 1) * 64, wn = (wave >> 1) * 64;
  long m0 = (long)blockIdx.y * 128;
  long n0 = (long)blockIdx.x * 128;
  const u16* Ab = A + m0 * K;
  const u16* Bb = B + n0 * K;
  if (MODE == 0 && tid == 0) bmax = 0u;
  f32x4 acc[4][4] = {};
  for (int k0 = 0; k0 < K; k0 += 64) {
#pragma unroll
    for (int i = 0; i < 4; i++) {
      int chunk = i * 256 + tid;  // 0..1023; lds dest = wave base + lane*16
      int row = chunk >> 3;
      int kc = (chunk & 7) * 8;
      ASYNC16(Ab + (long)row * K + k0 + kc, ((char*)As) + chunk * 16);
      ASYNC16(Bb + (long)row * K + k0 + kc, ((char*)Bs) + chunk * 16);
    }
    __syncthreads();
#pragma unroll
    for (int kk = 0; kk < 2; kk++) {
      bf16x8 af[4], bfr[4];
#pragma unroll
      for (int i = 0; i < 4; i++)
        af[i] = *(const bf16x8*)(As + (wm + i * 16 + l15) * 64 + kk * 32 +
                                 quad * 8);
#pragma unroll
      for (int j = 0; j < 4; j++)
        bfr[j] = *(const bf16x8*)(Bs + (wn + j * 16 + l15) * 64 + kk * 32 +
                                  quad * 8);
#pragma unroll
      for (int i = 0; i < 4; i++)
#pragma unroll
        for (int j = 0; j < 4; j++)
          acc[i][j] = __builtin_amdgcn_mfma_f32_16x16x32_bf16(
              af[i], bfr[j], acc[i][j], 0, 0, 0);
    }
    __syncthreads();
  }
  // epilogue
  float scale = load_scale(scales + sa) * load_scale(scales + sb);
  float biasv[4];
  float4 bl0[4], bl1[4];
#pragma unroll
  for (int j = 0; j < 4; j++) {
    long n = n0 + wn + j * 16 + l15;
    biasv[j] = bias[n];
    bl0[j] = ((const float4*)(Bl + n * 8))[0];
    bl1[j] = ((const float4*)(Bl + n * 8))[1];
  }
  float lmax = 0.0f;
#pragma unroll
  for (int i = 0; i < 4; i++) {
#pragma unroll
    for (int r = 0; r < 4; r++) {
      long m = m0 + wm + i * 16 + quad * 4 + r;
      float4 t0 = ((const float4*)(tl + m * 8))[0];
      float4 t1v = ((const float4*)(tl + m * 8))[1];
#pragma unroll
      for (int j = 0; j < 4; j++) {
        long n = n0 + wn + j * 16 + l15;
        float lora = t0.x * bl0[j].x + t0.y * bl0[j].y + t0.z * bl0[j].z +
                     t0.w * bl0[j].w + t1v.x * bl1[j].x + t1v.y * bl1[j].y +
                     t1v.z * bl1[j].z + t1v.w * bl1[j].w;
        float v = acc[i][j][r] * scale + biasv[j] + 2.0f * lora;
        if (MODE == 0) {
          float hv = 0.5f * v * (1.0f + erff(v * 0.70710678118654752f));
          __half hh = __float2half_rn(hv);
          ((u16*)outp)[m * N + n] = *(u16*)&hh;
          lmax = fmaxf(lmax, fabsf(hv));
        } else {
          ((float*)outp)[m * N + n] = v;
        }
      }
    }
  }
  if (MODE == 0) {
    atomicMax(&bmax, __float_as_uint(lmax));
    __syncthreads();
    if (tid == 0) atomicMax(hmax, bmax);
  }
}

extern "C" void kernel_launch(void* const* d_in, const int* in_sizes, int n_in,
                              void* d_out, int out_size, void* d_ws,
                              size_t ws_size, hipStream_t stream) {
  const float* x = (const float*)d_in[0];    // [8192][1024]
  const float* Wfc = (const float*)d_in[1];  // [4096][1024]
  const float* bfc = (const float*)d_in[2];  // [4096]
  const float* Afc = (const float*)d_in[3];  // [8][1024]
  const float* Bfc = (const float*)d_in[4];  // [4096][8]
  const float* Wpr = (const float*)d_in[5];  // [1024][4096]
  const float* bpr = (const float*)d_in[6];  // [1024]
  const float* Apr = (const float*)d_in[7];  // [8][4096]
  const float* Bpr = (const float*)d_in[8];  // [1024][8]
  float* out = (float*)d_out;                // fp32 [8192][1024]

  char* w = (char*)d_ws;
  u32* scales = (u32*)w;                   // 4 slots (fp32 bits): x, Wfc, Wpr, h
  float* t1 = (float*)(w + 256);           // [8192][8]
  float* t2 = (float*)(w + 256 + 262144);  // [8192][8]
  u16* xq = (u16*)(w + 524544);            // [8192][1024] bf16-int
  u16* wq1 = (u16*)(w + 17301760);         // [4096][1024] bf16-int
  u16* wq2 = (u16*)(w + 25690368);         // [1024][4096] bf16-int
  u16* hq = (u16*)(w + 34078976);          // [8192][4096] fp16 h, then bf16-int
  if (ws_size < 101187840) return;         // need ~96.5 MiB scratch

  hipMemsetAsync(scales, 0, 256, stream);
  absmax_kernel<<<1024, 256, 0, stream>>>(x, 8192 * 1024 / 4, scales + 0);
  absmax_kernel<<<512, 256, 0, stream>>>(Wfc, 4096 * 1024 / 4, scales + 1);
  absmax_kernel<<<512, 256, 0, stream>>>(Wpr, 4096 * 1024 / 4, scales + 2);
  quant_x_t1_kernel<<<8192, 256, 0, stream>>>(x, Afc, scales + 0, xq, t1);
  quant_w_kernel<<<512, 256, 0, stream>>>(Wfc, 4096 * 1024 / 4, scales + 1,
                                          wq1);
  quant_w_kernel<<<512, 256, 0, stream>>>(Wpr, 4096 * 1024 / 4, scales + 2,
                                          wq2);
  gemm_kernel<0><<<dim3(32, 64), 256, 0, stream>>>(
      xq, wq1, 4096, 1024, bfc, t1, Bfc, scales, 0, 1, hq, scales + 3);
  quant_h_t2_kernel<<<8192, 256, 0, stream>>>(hq, Apr, scales + 3, t2);
  gemm_kernel<1><<<dim3(8, 64), 256, 0, stream>>>(
      hq, wq2, 1024, 4096, bpr, t2, Bpr, scales, 3, 2, out, nullptr);
}

// Round 4
// 456.372 us; speedup vs baseline: 1.3575x; 1.3575x over previous
//
#include <hip/hip_runtime.h>
#include <hip/hip_bf16.h>
#include <hip/hip_fp16.h>
#include <math.h>

// QAT GPT2 MLP + LoRA on MI355X — fp32 in/out.
// Round 4: (1) XOR-swizzled LDS staging kills the 16-way bank conflict
// (2.5e7 -> ~0) in both GEMM fragment reads; (2) fast erf (A&S 7.1.26,
// |err|<=1.5e-7) replaces libm erff in gemm1 epilogue; (3) gemm2 uses a
// single-barrier double-buffered K-loop (raw s_waitcnt+s_barrier, m139
// pattern) because its 512-block grid = 2 blocks/CU cannot hide the
// vmcnt(0) barrier drain across blocks.

typedef unsigned short u16;
typedef unsigned int u32;
typedef short bf16x8 __attribute__((ext_vector_type(8)));
typedef float f32x4 __attribute__((ext_vector_type(4)));

#define ASYNC16(gp, lp)                                                        \
  __builtin_amdgcn_global_load_lds(                                            \
      (__attribute__((address_space(1))) void*)(gp),                           \
      (__attribute__((address_space(3))) void*)(lp), 16, 0, 0)

// quantize: q = clip(rint(v/s), -128, 127); q integer -> bf16 bits exact.
__device__ __forceinline__ u16 quant1(float v, float inv) {
  float q = rintf(v * inv);
  q = fminf(fmaxf(q, -128.0f), 127.0f);
  return (u16)(__float_as_uint(q) >> 16);
}

__device__ __forceinline__ float load_scale(const u32* slot) {
  return fmaxf(__uint_as_float(*slot) * (1.0f / 127.0f), 1e-8f);
}

// exact-erf GELU via Abramowitz-Stegun 7.1.26 (|erf err| <= 1.5e-7):
// erf(z) = 1 - (a1 t + ... + a5 t^5) exp(-z^2), t = 1/(1+0.3275911 z)
__device__ __forceinline__ float gelu_erf(float v) {
  float z = fabsf(v) * 0.70710678118654752f;
  float t = __builtin_amdgcn_rcpf(fmaf(0.3275911f, z, 1.0f));
  float poly =
      t * fmaf(t,
               fmaf(t,
                    fmaf(t, fmaf(t, 1.061405429f, -1.453152027f),
                         1.421413741f),
                    -0.284496736f),
               0.254829592f);
  float e = fmaf(-poly, exp2f(-z * z * 1.4426950408889634f), 1.0f);
  return 0.5f * v * fmaf(copysignf(e, v), 1.0f, 1.0f);
}

// -------------------- absmax over fp32 tensor (float4 grid-stride) ----------
__global__ void absmax_kernel(const float* __restrict__ x, int n4,
                              u32* __restrict__ slot) {
  float m = 0.0f;
  int stride = gridDim.x * blockDim.x;
  for (int i = blockIdx.x * blockDim.x + threadIdx.x; i < n4; i += stride) {
    float4 v = ((const float4*)x)[i];
    m = fmaxf(m, fmaxf(fmaxf(fabsf(v.x), fabsf(v.y)),
                       fmaxf(fabsf(v.z), fabsf(v.w))));
  }
#pragma unroll
  for (int off = 32; off > 0; off >>= 1) m = fmaxf(m, __shfl_down(m, off));
  __shared__ float wmax[4];
  int lane = threadIdx.x & 63, wave = threadIdx.x >> 6;
  if (lane == 0) wmax[wave] = m;
  __syncthreads();
  if (threadIdx.x == 0) {
    m = fmaxf(fmaxf(wmax[0], wmax[1]), fmaxf(wmax[2], wmax[3]));
    atomicMax(slot, __float_as_uint(m));  // positive floats: bit-monotone
  }
}

// -------------------- quantize W (fp32 in, bf16-int out) --------------------
__global__ void quant_w_kernel(const float* __restrict__ w, int n4,
                               const u32* __restrict__ slot,
                               u16* __restrict__ q) {
  float inv = 1.0f / load_scale(slot);
  int stride = gridDim.x * blockDim.x;
  for (int i = blockIdx.x * blockDim.x + threadIdx.x; i < n4; i += stride) {
    float4 v = ((const float4*)w)[i];
    ushort4 o;
    o.x = quant1(v.x, inv);
    o.y = quant1(v.y, inv);
    o.z = quant1(v.z, inv);
    o.w = quant1(v.w, inv);
    ((ushort4*)q)[i] = o;
  }
}

// ---- quantize x + t1[m][r] = sum_i x[m,i]*Afc[r,i]  (block per row) --------
__global__ void quant_x_t1_kernel(const float* __restrict__ x,
                                  const float* __restrict__ A,  // [8][1024]
                                  const u32* __restrict__ slot,
                                  u16* __restrict__ q,
                                  float* __restrict__ t1) {
  int row = blockIdx.x, tid = threadIdx.x;
  float inv = 1.0f / load_scale(slot);
  float4 v = ((const float4*)(x + (long)row * 1024))[tid];
  ushort4 o;
  o.x = quant1(v.x, inv);
  o.y = quant1(v.y, inv);
  o.z = quant1(v.z, inv);
  o.w = quant1(v.w, inv);
  ((ushort4*)(q + (long)row * 1024))[tid] = o;
  float p[8];
#pragma unroll
  for (int r = 0; r < 8; r++) {
    float4 a = ((const float4*)(A + r * 1024))[tid];
    p[r] = v.x * a.x + v.y * a.y + v.z * a.z + v.w * a.w;
  }
#pragma unroll
  for (int r = 0; r < 8; r++)
#pragma unroll
    for (int off = 32; off > 0; off >>= 1) p[r] += __shfl_down(p[r], off);
  __shared__ float red[4][8];
  int lane = tid & 63, wave = tid >> 6;
  if (lane == 0) {
#pragma unroll
    for (int r = 0; r < 8; r++) red[wave][r] = p[r];
  }
  __syncthreads();
  if (tid < 8)
    t1[(long)row * 8 + tid] =
        red[0][tid] + red[1][tid] + red[2][tid] + red[3][tid];
}

// ---- quantize h (fp16 in, bf16-int out, in place) + t2 = h@Aproj^T ---------
__global__ void quant_h_t2_kernel(u16* __restrict__ h,  // [8192][4096] fp16
                                  const float* __restrict__ A,  // [8][4096]
                                  const u32* __restrict__ slot,
                                  float* __restrict__ t2) {
  int row = blockIdx.x, tid = threadIdx.x;
  float inv = 1.0f / load_scale(slot);
  u16* hp = h + (long)row * 4096 + tid * 16;
  uint4 u0 = ((const uint4*)hp)[0];
  uint4 u1 = ((const uint4*)hp)[1];
  u32 uu[8] = {u0.x, u0.y, u0.z, u0.w, u1.x, u1.y, u1.z, u1.w};
  float hv[16];
#pragma unroll
  for (int e = 0; e < 8; e++) {
    __half2 hh = *(__half2*)&uu[e];
    float2 f = __half22float2(hh);
    hv[2 * e] = f.x;
    hv[2 * e + 1] = f.y;
  }
  const float* Ab = A + tid * 16;
  float p[8];
#pragma unroll
  for (int r = 0; r < 8; r++) {
    const float4* Ar = (const float4*)(Ab + r * 4096);
    float s = 0.0f;
#pragma unroll
    for (int c = 0; c < 4; c++) {
      float4 a = Ar[c];
      s += a.x * hv[c * 4 + 0] + a.y * hv[c * 4 + 1] + a.z * hv[c * 4 + 2] +
           a.w * hv[c * 4 + 3];
    }
    p[r] = s;
  }
  u32 qu[8];
#pragma unroll
  for (int e = 0; e < 8; e++) {
    u16 q0 = quant1(hv[2 * e], inv);
    u16 q1 = quant1(hv[2 * e + 1], inv);
    qu[e] = (u32)q0 | ((u32)q1 << 16);
  }
  uint4 w0 = {qu[0], qu[1], qu[2], qu[3]};
  uint4 w1 = {qu[4], qu[5], qu[6], qu[7]};
  ((uint4*)hp)[0] = w0;
  ((uint4*)hp)[1] = w1;
#pragma unroll
  for (int r = 0; r < 8; r++)
#pragma unroll
    for (int off = 32; off > 0; off >>= 1) p[r] += __shfl_down(p[r], off);
  __shared__ float red[4][8];
  int lane = tid & 63, wave = tid >> 6;
  if (lane == 0) {
#pragma unroll
    for (int r = 0; r < 8; r++) red[wave][r] = p[r];
  }
  __syncthreads();
  if (tid < 8)
    t2[(long)row * 8 + tid] =
        red[0][tid] + red[1][tid] + red[2][tid] + red[3][tid];
}

// -------------------- main GEMM: C = Aq * Bq^T, 128x128 tile ----------------
// LDS layout is XOR-swizzled: phys k-chunk p at row r holds logical chunk
// p ^ (r&7)  (chunk = 16 B = 8 u16). Staging permutes the global source
// (global_load_lds write side is fixed: lane-contiguous); fragment reads
// apply the same xor => every ds_read_b128 is bank-balanced (2 lanes/bank).
// MODE 0: *scale + bias + 2*t.Bl, GELU(erf), store FP16 h, absmax(h).
// MODE 1: *scale + bias + 2*t.Bl, store fp32 to d_out.
// DBUF 1: single-barrier double-buffered K-loop (raw s_waitcnt+s_barrier).
template <int MODE, int DBUF>
__launch_bounds__(256) __global__
    void gemm_kernel(const u16* __restrict__ A, const u16* __restrict__ B,
                     int N, int K, const float* __restrict__ bias,
                     const float* __restrict__ tl,   // [M][8] f32
                     const float* __restrict__ Bl,   // [N][8] f32
                     const u32* __restrict__ scales, int sa, int sb,
                     void* __restrict__ outp, u32* __restrict__ hmax) {
  constexpr int NB = DBUF ? 2 : 1;
  __shared__ u16 As[NB * 128 * 64];
  __shared__ u16 Bs[NB * 128 * 64];
  __shared__ u32 bmax;
  int tid = threadIdx.x;
  int lane = tid & 63, wave = tid >> 6;
  int quad = lane >> 4, l15 = lane & 15;
  int wm = (wave & 1) * 64, wn = (wave >> 1) * 64;
  long m0 = (long)blockIdx.y * 128;
  long n0 = (long)blockIdx.x * 128;
  if (MODE == 0 && tid == 0) bmax = 0u;

  // staging source pointers (swizzled k-chunk), advanced 64 elems per iter
  const u16* gA[4];
  const u16* gB[4];
  int ldsOff[4];
#pragma unroll
  for (int i = 0; i < 4; i++) {
    int c = i * 256 + tid;          // chunk index 0..1023
    int row = c >> 3;               // tile row 0..127
    int kc = ((c & 7) ^ (row & 7)) * 8;  // swizzled source k-offset (elems)
    gA[i] = A + (m0 + row) * K + kc;
    gB[i] = B + (n0 + row) * K + kc;
    ldsOff[i] = c * 16;             // byte offset of phys chunk
  }
  // fragment-read swizzled chunk offsets (elems): chunk = (kk*4+quad)^(l15&7)
  int s0 = ((quad ^ (l15 & 7)) * 8);
  int s1 = s0 ^ 32;  // (4+quad)^(l15&7) == (quad^(l15&7)) xor 4 -> +-32 elems

  f32x4 acc[4][4] = {};
  int nit = K >> 6;

#define ISSUE(bo)                                                              \
  {                                                                            \
    _Pragma("unroll") for (int i = 0; i < 4; i++) {                            \
      ASYNC16(gA[i], ((char*)As) + (bo)*2 + ldsOff[i]);                        \
      ASYNC16(gB[i], ((char*)Bs) + (bo)*2 + ldsOff[i]);                        \
      gA[i] += 64;                                                             \
      gB[i] += 64;                                                             \
    }                                                                          \
  }
#define COMPUTE(bo)                                                            \
  {                                                                            \
    _Pragma("unroll") for (int kk = 0; kk < 2; kk++) {                         \
      int ko = kk ? s1 : s0;                                                   \
      bf16x8 af[4], bfr[4];                                                    \
      _Pragma("unroll") for (int i = 0; i < 4; i++) af[i] =                    \
          *(const bf16x8*)(As + (bo) + (wm + i * 16 + l15) * 64 + ko);         \
      _Pragma("unroll") for (int j = 0; j < 4; j++) bfr[j] =                   \
          *(const bf16x8*)(Bs + (bo) + (wn + j * 16 + l15) * 64 + ko);         \
      _Pragma("unroll") for (int i = 0; i < 4; i++)                            \
          _Pragma("unroll") for (int j = 0; j < 4; j++) acc[i][j] =            \
              __builtin_amdgcn_mfma_f32_16x16x32_bf16(af[i], bfr[j],           \
                                                      acc[i][j], 0, 0, 0);     \
    }                                                                          \
  }

  if (DBUF) {
    ISSUE(0);
    for (int k = 0; k < nit; k++) {
      // wait own staged loads for buf[k&1], then join; all waves' tile data
      // is then visible. Prefetch issued AFTER the barrier so no wave can
      // still be reading the target buffer (it was computed pre-barrier).
      asm volatile("s_waitcnt vmcnt(0)\n\ts_barrier" ::: "memory");
      if (k + 1 < nit) ISSUE(((k + 1) & 1) * 8192);
      COMPUTE((k & 1) * 8192);
    }
  } else {
    for (int k = 0; k < nit; k++) {
      ISSUE(0);
      __syncthreads();
      COMPUTE(0);
      __syncthreads();
    }
  }
#undef ISSUE
#undef COMPUTE

  // epilogue
  float scale = load_scale(scales + sa) * load_scale(scales + sb);
  float biasv[4];
  float4 bl0[4], bl1[4];
#pragma unroll
  for (int j = 0; j < 4; j++) {
    long n = n0 + wn + j * 16 + l15;
    biasv[j] = bias[n];
    bl0[j] = ((const float4*)(Bl + n * 8))[0];
    bl1[j] = ((const float4*)(Bl + n * 8))[1];
  }
  float lmax = 0.0f;
#pragma unroll
  for (int i = 0; i < 4; i++) {
#pragma unroll
    for (int r = 0; r < 4; r++) {
      long m = m0 + wm + i * 16 + quad * 4 + r;
      float4 t0 = ((const float4*)(tl + m * 8))[0];
      float4 t1v = ((const float4*)(tl + m * 8))[1];
#pragma unroll
      for (int j = 0; j < 4; j++) {
        long n = n0 + wn + j * 16 + l15;
        float lora = t0.x * bl0[j].x + t0.y * bl0[j].y + t0.z * bl0[j].z +
                     t0.w * bl0[j].w + t1v.x * bl1[j].x + t1v.y * bl1[j].y +
                     t1v.z * bl1[j].z + t1v.w * bl1[j].w;
        float v = acc[i][j][r] * scale + biasv[j] + 2.0f * lora;
        if (MODE == 0) {
          float hv = gelu_erf(v);
          __half hh = __float2half_rn(hv);
          ((u16*)outp)[m * N + n] = *(u16*)&hh;
          lmax = fmaxf(lmax, fabsf(hv));
        } else {
          ((float*)outp)[m * N + n] = v;
        }
      }
    }
  }
  if (MODE == 0) {
    atomicMax(&bmax, __float_as_uint(lmax));
    __syncthreads();
    if (tid == 0) atomicMax(hmax, bmax);
  }
}

extern "C" void kernel_launch(void* const* d_in, const int* in_sizes, int n_in,
                              void* d_out, int out_size, void* d_ws,
                              size_t ws_size, hipStream_t stream) {
  const float* x = (const float*)d_in[0];    // [8192][1024]
  const float* Wfc = (const float*)d_in[1];  // [4096][1024]
  const float* bfc = (const float*)d_in[2];  // [4096]
  const float* Afc = (const float*)d_in[3];  // [8][1024]
  const float* Bfc = (const float*)d_in[4];  // [4096][8]
  const float* Wpr = (const float*)d_in[5];  // [1024][4096]
  const float* bpr = (const float*)d_in[6];  // [1024]
  const float* Apr = (const float*)d_in[7];  // [8][4096]
  const float* Bpr = (const float*)d_in[8];  // [1024][8]
  float* out = (float*)d_out;                // fp32 [8192][1024]

  char* w = (char*)d_ws;
  u32* scales = (u32*)w;                   // 4 slots (fp32 bits): x, Wfc, Wpr, h
  float* t1 = (float*)(w + 256);           // [8192][8]
  float* t2 = (float*)(w + 256 + 262144);  // [8192][8]
  u16* xq = (u16*)(w + 524544);            // [8192][1024] bf16-int
  u16* wq1 = (u16*)(w + 17301760);         // [4096][1024] bf16-int
  u16* wq2 = (u16*)(w + 25690368);         // [1024][4096] bf16-int
  u16* hq = (u16*)(w + 34078976);          // [8192][4096] fp16 h, then bf16-int
  if (ws_size < 101187840) return;         // need ~96.5 MiB scratch

  hipMemsetAsync(scales, 0, 256, stream);
  absmax_kernel<<<1024, 256, 0, stream>>>(x, 8192 * 1024 / 4, scales + 0);
  absmax_kernel<<<512, 256, 0, stream>>>(Wfc, 4096 * 1024 / 4, scales + 1);
  absmax_kernel<<<512, 256, 0, stream>>>(Wpr, 4096 * 1024 / 4, scales + 2);
  quant_x_t1_kernel<<<8192, 256, 0, stream>>>(x, Afc, scales + 0, xq, t1);
  quant_w_kernel<<<512, 256, 0, stream>>>(Wfc, 4096 * 1024 / 4, scales + 1,
                                          wq1);
  quant_w_kernel<<<512, 256, 0, stream>>>(Wpr, 4096 * 1024 / 4, scales + 2,
                                          wq2);
  gemm_kernel<0, 0><<<dim3(32, 64), 256, 0, stream>>>(
      xq, wq1, 4096, 1024, bfc, t1, Bfc, scales, 0, 1, hq, scales + 3);
  quant_h_t2_kernel<<<8192, 256, 0, stream>>>(hq, Apr, scales + 3, t2);
  gemm_kernel<1, 1><<<dim3(8, 64), 256, 0, stream>>>(
      hq, wq2, 1024, 4096, bpr, t2, Bpr, scales, 3, 2, out, nullptr);
}

// Round 5
// 387.284 us; speedup vs baseline: 1.5997x; 1.1784x over previous
//
#include <hip/hip_runtime.h>
#include <hip/hip_bf16.h>
#include <hip/hip_fp16.h>
#include <math.h>

// QAT GPT2 MLP + LoRA on MI355X — fp32 in/out.
// Round 5: int8 MFMA (v_mfma_i32_16x16x64_i8) on the quantized values —
// halves LDS read bytes/MAC (round-4 counters proved the K-loop is
// LDS-BW-bound: 64 KB/iter = 770 cyc/iter = measured per-iter time),
// halves staging traffic, doubles MFMA K-density. i32 accumulation exact.
// gemm2 reverted to the 2-barrier K-loop (round-4 single-barrier DBUF
// regressed ~70us, consistent with m99/m131-141). XOR-swizzled LDS kept
// (conflicts 2.5e7 -> 0 measured). Fast erf GELU kept.

typedef unsigned short u16;
typedef unsigned int u32;
typedef signed char i8;
typedef int i32x4 __attribute__((ext_vector_type(4)));

#define ASYNC16(gp, lp)                                                        \
  __builtin_amdgcn_global_load_lds(                                            \
      (__attribute__((address_space(1))) void*)(gp),                           \
      (__attribute__((address_space(3))) void*)(lp), 16, 0, 0)

// quantize to int: q = clip(rint(v/s), -128, 127)
__device__ __forceinline__ int quanti(float v, float inv) {
  float q = rintf(v * inv);
  q = fminf(fmaxf(q, -128.0f), 127.0f);
  return (int)q;
}

__device__ __forceinline__ float load_scale(const u32* slot) {
  return fmaxf(__uint_as_float(*slot) * (1.0f / 127.0f), 1e-8f);
}

// exact-erf GELU via Abramowitz-Stegun 7.1.26 (|erf err| <= 1.5e-7)
__device__ __forceinline__ float gelu_erf(float v) {
  float z = fabsf(v) * 0.70710678118654752f;
  float t = __builtin_amdgcn_rcpf(fmaf(0.3275911f, z, 1.0f));
  float poly =
      t * fmaf(t,
               fmaf(t,
                    fmaf(t, fmaf(t, 1.061405429f, -1.453152027f),
                         1.421413741f),
                    -0.284496736f),
               0.254829592f);
  float e = fmaf(-poly, exp2f(-z * z * 1.4426950408889634f), 1.0f);
  return 0.5f * v * fmaf(copysignf(e, v), 1.0f, 1.0f);
}

// -------------------- absmax over fp32 tensor (float4 grid-stride) ----------
__global__ void absmax_kernel(const float* __restrict__ x, int n4,
                              u32* __restrict__ slot) {
  float m = 0.0f;
  int stride = gridDim.x * blockDim.x;
  for (int i = blockIdx.x * blockDim.x + threadIdx.x; i < n4; i += stride) {
    float4 v = ((const float4*)x)[i];
    m = fmaxf(m, fmaxf(fmaxf(fabsf(v.x), fabsf(v.y)),
                       fmaxf(fabsf(v.z), fabsf(v.w))));
  }
#pragma unroll
  for (int off = 32; off > 0; off >>= 1) m = fmaxf(m, __shfl_down(m, off));
  __shared__ float wmax[4];
  int lane = threadIdx.x & 63, wave = threadIdx.x >> 6;
  if (lane == 0) wmax[wave] = m;
  __syncthreads();
  if (threadIdx.x == 0) {
    m = fmaxf(fmaxf(wmax[0], wmax[1]), fmaxf(wmax[2], wmax[3]));
    atomicMax(slot, __float_as_uint(m));  // positive floats: bit-monotone
  }
}

// ---------------- quantize W (fp32 in, packed i8 out) -----------------------
// each thread handles 16 floats -> one uint4 (16 i8) store
__global__ void quant_w_kernel(const float* __restrict__ w, int n16,
                               const u32* __restrict__ slot,
                               i8* __restrict__ q) {
  float inv = 1.0f / load_scale(slot);
  int stride = gridDim.x * blockDim.x;
  for (int i = blockIdx.x * blockDim.x + threadIdx.x; i < n16; i += stride) {
    const float4* src = (const float4*)w + i * 4;
    u32 pk[4];
#pragma unroll
    for (int c = 0; c < 4; c++) {
      float4 v = src[c];
      pk[c] = ((u32)(quanti(v.x, inv) & 255)) |
              ((u32)(quanti(v.y, inv) & 255) << 8) |
              ((u32)(quanti(v.z, inv) & 255) << 16) |
              ((u32)(quanti(v.w, inv) & 255) << 24);
    }
    uint4 o = {pk[0], pk[1], pk[2], pk[3]};
    ((uint4*)q)[i] = o;
  }
}

// ---- quantize x + t1[m][r] = sum_i x[m,i]*Afc[r,i]  (block per row) --------
__global__ void quant_x_t1_kernel(const float* __restrict__ x,
                                  const float* __restrict__ A,  // [8][1024]
                                  const u32* __restrict__ slot,
                                  i8* __restrict__ q,
                                  float* __restrict__ t1) {
  int row = blockIdx.x, tid = threadIdx.x;
  float inv = 1.0f / load_scale(slot);
  float4 v = ((const float4*)(x + (long)row * 1024))[tid];
  u32 pk = ((u32)(quanti(v.x, inv) & 255)) |
           ((u32)(quanti(v.y, inv) & 255) << 8) |
           ((u32)(quanti(v.z, inv) & 255) << 16) |
           ((u32)(quanti(v.w, inv) & 255) << 24);
  ((u32*)(q + (long)row * 1024))[tid] = pk;
  float p[8];
#pragma unroll
  for (int r = 0; r < 8; r++) {
    float4 a = ((const float4*)(A + r * 1024))[tid];
    p[r] = v.x * a.x + v.y * a.y + v.z * a.z + v.w * a.w;
  }
#pragma unroll
  for (int r = 0; r < 8; r++)
#pragma unroll
    for (int off = 32; off > 0; off >>= 1) p[r] += __shfl_down(p[r], off);
  __shared__ float red[4][8];
  int lane = tid & 63, wave = tid >> 6;
  if (lane == 0) {
#pragma unroll
    for (int r = 0; r < 8; r++) red[wave][r] = p[r];
  }
  __syncthreads();
  if (tid < 8)
    t1[(long)row * 8 + tid] =
        red[0][tid] + red[1][tid] + red[2][tid] + red[3][tid];
}

// ---- quantize h (fp16 in; i8 out IN PLACE, first half of each fp16 row) ----
// + t2[m][r] = sum_k h[m,k]*Aproj[r,k]
__global__ void quant_h_t2_kernel(u16* __restrict__ h,  // [8192][4096] fp16
                                  const float* __restrict__ A,  // [8][4096]
                                  const u32* __restrict__ slot,
                                  float* __restrict__ t2) {
  int row = blockIdx.x, tid = threadIdx.x;
  float inv = 1.0f / load_scale(slot);
  u16* hp = h + (long)row * 4096 + tid * 16;
  uint4 u0 = ((const uint4*)hp)[0];
  uint4 u1 = ((const uint4*)hp)[1];
  u32 uu[8] = {u0.x, u0.y, u0.z, u0.w, u1.x, u1.y, u1.z, u1.w};
  float hv[16];
#pragma unroll
  for (int e = 0; e < 8; e++) {
    __half2 hh = *(__half2*)&uu[e];
    float2 f = __half22float2(hh);
    hv[2 * e] = f.x;
    hv[2 * e + 1] = f.y;
  }
  const float* Ab = A + tid * 16;
  float p[8];
#pragma unroll
  for (int r = 0; r < 8; r++) {
    const float4* Ar = (const float4*)(Ab + r * 4096);
    float s = 0.0f;
#pragma unroll
    for (int c = 0; c < 4; c++) {
      float4 a = Ar[c];
      s += a.x * hv[c * 4 + 0] + a.y * hv[c * 4 + 1] + a.z * hv[c * 4 + 2] +
           a.w * hv[c * 4 + 3];
    }
    p[r] = s;
  }
  // all reads of this row are done (hv consumed); barrier, then overwrite
  // the first half of the row with packed i8.
  __syncthreads();
  u32 pk[4];
#pragma unroll
  for (int c = 0; c < 4; c++) {
    pk[c] = ((u32)(quanti(hv[4 * c + 0], inv) & 255)) |
            ((u32)(quanti(hv[4 * c + 1], inv) & 255) << 8) |
            ((u32)(quanti(hv[4 * c + 2], inv) & 255) << 16) |
            ((u32)(quanti(hv[4 * c + 3], inv) & 255) << 24);
  }
  uint4 o = {pk[0], pk[1], pk[2], pk[3]};
  *(uint4*)((i8*)h + (long)row * 8192 + tid * 16) = o;
#pragma unroll
  for (int r = 0; r < 8; r++)
#pragma unroll
    for (int off = 32; off > 0; off >>= 1) p[r] += __shfl_down(p[r], off);
  __shared__ float red[4][8];
  int lane = tid & 63, wave = tid >> 6;
  if (lane == 0) {
#pragma unroll
    for (int r = 0; r < 8; r++) red[wave][r] = p[r];
  }
  __syncthreads();
  if (tid < 8)
    t2[(long)row * 8 + tid] =
        red[0][tid] + red[1][tid] + red[2][tid] + red[3][tid];
}

// ------------- main GEMM: C = Aq * Bq^T (i8), 128x128 tile, BK=128 ---------
// A: [M] rows stride lda bytes, B: [N] rows stride ldb bytes, K-major i8.
// LDS XOR-swizzle: phys 16B-chunk p at row r holds logical chunk p^(r&7).
// MFMA: v_mfma_i32_16x16x64_i8, A-frag = 16 i8 at [m=l15][k=quad*16+j].
// MODE 0: *scale + bias + 2*t.Bl, GELU(erf), store FP16 h, absmax(h).
// MODE 1: *scale + bias + 2*t.Bl, store fp32 to d_out.
template <int MODE>
__launch_bounds__(256) __global__
    void gemm_kernel(const i8* __restrict__ A, const i8* __restrict__ B,
                     int N, int K, int lda, int ldb,
                     const float* __restrict__ bias,
                     const float* __restrict__ tl,   // [M][8] f32
                     const float* __restrict__ Bl,   // [N][8] f32
                     const u32* __restrict__ scales, int sa, int sb,
                     void* __restrict__ outp, u32* __restrict__ hmax) {
  __shared__ i8 As[128 * 128];
  __shared__ i8 Bs[128 * 128];
  __shared__ u32 bmax;
  int tid = threadIdx.x;
  int lane = tid & 63, wave = tid >> 6;
  int quad = lane >> 4, l15 = lane & 15;
  int wm = (wave & 1) * 64, wn = (wave >> 1) * 64;
  long m0 = (long)blockIdx.y * 128;
  long n0 = (long)blockIdx.x * 128;
  if (MODE == 0 && tid == 0) bmax = 0u;

  // staging: 1024 chunks of 16B per operand; row = c>>3, swizzled k-chunk
  const i8* gA[4];
  const i8* gB[4];
  int ldsOff[4];
#pragma unroll
  for (int i = 0; i < 4; i++) {
    int c = i * 256 + tid;
    int row = c >> 3;
    int kc = ((c & 7) ^ (row & 7)) * 16;  // swizzled source k-offset (bytes)
    gA[i] = A + (m0 + row) * lda + kc;
    gB[i] = B + (n0 + row) * ldb + kc;
    ldsOff[i] = c * 16;
  }
  // fragment-read swizzled chunk byte offsets: chunk = (kk*4+quad)^(l15&7)
  int s0 = (quad ^ (l15 & 7)) * 16;
  int s1 = s0 ^ 64;

  i32x4 acc[4][4] = {};
  int nit = K >> 7;
  for (int k = 0; k < nit; k++) {
#pragma unroll
    for (int i = 0; i < 4; i++) {
      ASYNC16(gA[i], As + ldsOff[i]);
      ASYNC16(gB[i], Bs + ldsOff[i]);
      gA[i] += 128;
      gB[i] += 128;
    }
    __syncthreads();
#pragma unroll
    for (int kk = 0; kk < 2; kk++) {
      int ko = kk ? s1 : s0;
      i32x4 af[4], bfr[4];
#pragma unroll
      for (int i = 0; i < 4; i++)
        af[i] = *(const i32x4*)(As + (wm + i * 16 + l15) * 128 + ko);
#pragma unroll
      for (int j = 0; j < 4; j++)
        bfr[j] = *(const i32x4*)(Bs + (wn + j * 16 + l15) * 128 + ko);
#pragma unroll
      for (int i = 0; i < 4; i++)
#pragma unroll
        for (int j = 0; j < 4; j++)
          acc[i][j] = __builtin_amdgcn_mfma_i32_16x16x64_i8(
              af[i], bfr[j], acc[i][j], 0, 0, 0);
    }
    __syncthreads();
  }

  // epilogue
  float scale = load_scale(scales + sa) * load_scale(scales + sb);
  float biasv[4];
  float4 bl0[4], bl1[4];
#pragma unroll
  for (int j = 0; j < 4; j++) {
    long n = n0 + wn + j * 16 + l15;
    biasv[j] = bias[n];
    bl0[j] = ((const float4*)(Bl + n * 8))[0];
    bl1[j] = ((const float4*)(Bl + n * 8))[1];
  }
  float lmax = 0.0f;
#pragma unroll
  for (int i = 0; i < 4; i++) {
#pragma unroll
    for (int r = 0; r < 4; r++) {
      long m = m0 + wm + i * 16 + quad * 4 + r;
      float4 t0 = ((const float4*)(tl + m * 8))[0];
      float4 t1v = ((const float4*)(tl + m * 8))[1];
#pragma unroll
      for (int j = 0; j < 4; j++) {
        long n = n0 + wn + j * 16 + l15;
        float lora = t0.x * bl0[j].x + t0.y * bl0[j].y + t0.z * bl0[j].z +
                     t0.w * bl0[j].w + t1v.x * bl1[j].x + t1v.y * bl1[j].y +
                     t1v.z * bl1[j].z + t1v.w * bl1[j].w;
        float v = (float)acc[i][j][r] * scale + biasv[j] + 2.0f * lora;
        if (MODE == 0) {
          float hv = gelu_erf(v);
          __half hh = __float2half_rn(hv);
          ((u16*)outp)[m * N + n] = *(u16*)&hh;
          lmax = fmaxf(lmax, fabsf(hv));
        } else {
          ((float*)outp)[m * N + n] = v;
        }
      }
    }
  }
  if (MODE == 0) {
    atomicMax(&bmax, __float_as_uint(lmax));
    __syncthreads();
    if (tid == 0) atomicMax(hmax, bmax);
  }
}

extern "C" void kernel_launch(void* const* d_in, const int* in_sizes, int n_in,
                              void* d_out, int out_size, void* d_ws,
                              size_t ws_size, hipStream_t stream) {
  const float* x = (const float*)d_in[0];    // [8192][1024]
  const float* Wfc = (const float*)d_in[1];  // [4096][1024]
  const float* bfc = (const float*)d_in[2];  // [4096]
  const float* Afc = (const float*)d_in[3];  // [8][1024]
  const float* Bfc = (const float*)d_in[4];  // [4096][8]
  const float* Wpr = (const float*)d_in[5];  // [1024][4096]
  const float* bpr = (const float*)d_in[6];  // [1024]
  const float* Apr = (const float*)d_in[7];  // [8][4096]
  const float* Bpr = (const float*)d_in[8];  // [1024][8]
  float* out = (float*)d_out;                // fp32 [8192][1024]

  char* w = (char*)d_ws;
  u32* scales = (u32*)w;                   // 4 slots (fp32 bits): x, Wfc, Wpr, h
  float* t1 = (float*)(w + 256);           // [8192][8]
  float* t2 = (float*)(w + 256 + 262144);  // [8192][8]
  i8* xq = (i8*)(w + 524544);              // [8192][1024] i8
  i8* wq1 = (i8*)(w + 9437184);            // [4096][1024] i8
  i8* wq2 = (i8*)(w + 13631488);           // [1024][4096] i8
  u16* hq = (u16*)(w + 17825792);          // [8192][4096] fp16 h; i8 in place
  if (ws_size < 84934656) return;          // need ~81 MiB scratch

  hipMemsetAsync(scales, 0, 256, stream);
  absmax_kernel<<<1024, 256, 0, stream>>>(x, 8192 * 1024 / 4, scales + 0);
  absmax_kernel<<<512, 256, 0, stream>>>(Wfc, 4096 * 1024 / 4, scales + 1);
  absmax_kernel<<<512, 256, 0, stream>>>(Wpr, 4096 * 1024 / 4, scales + 2);
  quant_x_t1_kernel<<<8192, 256, 0, stream>>>(x, Afc, scales + 0, xq, t1);
  quant_w_kernel<<<256, 256, 0, stream>>>(Wfc, 4096 * 1024 / 16, scales + 1,
                                          wq1);
  quant_w_kernel<<<256, 256, 0, stream>>>(Wpr, 4096 * 1024 / 16, scales + 2,
                                          wq2);
  gemm_kernel<0><<<dim3(32, 64), 256, 0, stream>>>(
      xq, wq1, 4096, 1024, 1024, 1024, bfc, t1, Bfc, scales, 0, 1, hq,
      scales + 3);
  quant_h_t2_kernel<<<8192, 256, 0, stream>>>(hq, Apr, scales + 3, t2);
  gemm_kernel<1><<<dim3(8, 64), 256, 0, stream>>>(
      (const i8*)hq, wq2, 1024, 4096, 8192, 4096, bpr, t2, Bpr, scales, 3, 2,
      out, nullptr);
}